// Round 1
// baseline (407.498 us; speedup 1.0000x reference)
//
#include <hip/hip_runtime.h>
#include <math.h>

// RVQECell on MI355X.
// State: [B=32][2^19] fp32. Lane l <-> state bit (18-l). inout = bits 13..18,
// work = bits 1..12, ancilla = bit 0 (spectator).
//
// Pipeline:
//  K1 tables_kernel : 54 neuron tables (cos a, sin a)[2^17] into d_ws (54 MiB).
//  K2 main_kernel   : per (batch, inout-block): load 8192 floats to LDS, apply
//                     input layer + 3x(unitary+neuron) layers fused as 28
//                     triple-bit LDS passes; bitflips folded into table index
//                     (vt = u ^ fb). Writes post-second-bitflip state to psi.
//  K3 out_kernel    : per column (low 13 bits): 64 amps in registers, 6 output
//                     neurons, write final psi.
//  K4 probs_kernel  : probs[b,v] = sum of psi^2 over the 8192-block.

#define BIAS_F 1.57079632679489662f

// ---- LDS bank swizzle: fold bits 7..5 into 4..2 (keeps float4 contiguity) ----
__device__ __forceinline__ int SW(int i) { return i ^ ((i >> 3) & 0x1C); }
__device__ __forceinline__ float4 ldsld4(const float* st, int i) {
    return *(const float4*)&st[SW(i)];
}
__device__ __forceinline__ void ldsst4(float* st, int i, float4 v) {
    *(float4*)&st[SW(i)] = v;
}
#define T4(t, i) (*(const float4*)&(t)[i])

// rotation on pairs (A.k, B.k); e = (c01,s01,c23,s23)
__device__ __forceinline__ void rot4(float4& A, float4& B, float4 e) {
    float ax = A.x, ay = A.y, az = A.z, aw = A.w;
    A.x = e.x * ax - e.y * B.x;  B.x = e.y * ax + e.x * B.x;
    A.y = e.x * ay - e.y * B.y;  B.y = e.y * ay + e.x * B.y;
    A.z = e.z * az - e.w * B.z;  B.z = e.w * az + e.z * B.z;
    A.w = e.z * aw - e.w * B.w;  B.w = e.w * aw + e.z * B.w;
}
// rotation within a quad: pairs (x,z),(y,w)
__device__ __forceinline__ void rotq(float4& P, float c, float s) {
    float px = P.x, py = P.y;
    P.x = c * px - s * P.z;  P.z = s * px + c * P.z;
    P.y = c * py - s * P.w;  P.w = s * py + c * P.w;
}

// ============================ K1: tables ============================
// grid (512, 54), block 256. x = (blockIdx.x << 8) | tid ; control i <-> x bit (16-i).
__global__ __launch_bounds__(256) void tables_kernel(
    const float* __restrict__ w_in1, const float* __restrict__ w_in2,
    const float* __restrict__ w_k1,  const float* __restrict__ w_k2,
    const float* __restrict__ w_out1, const float* __restrict__ w_out2,
    float2* __restrict__ tab)
{
    const int n = blockIdx.y;
    const int hi = blockIdx.x;       // x bits 16..8 (uniform per block)
    const int tid = threadIdx.x;     // x bits 7..0
    const float* th1;
    const float* th2;
    if (n < 12)      { th1 = w_in1 + n * 17;         th2 = w_in2 + n * 289; }
    else if (n < 48) { th1 = w_k1 + (n - 12) * 17;   th2 = w_k2 + (n - 12) * 289; }
    else             { th1 = w_out1 + (n - 48) * 17; th2 = w_out2 + (n - 48) * 289; }

    float bu[9], bt[8];
#pragma unroll
    for (int i = 0; i < 9; ++i) bu[i] = (float)((hi >> (8 - i)) & 1);
#pragma unroll
    for (int j = 0; j < 8; ++j) bt[j] = (float)((tid >> (7 - j)) & 1);

    float phi = BIAS_F;
#pragma unroll
    for (int i = 0; i < 9; ++i) {
        float acc = th1[i];
#pragma unroll
        for (int j = i + 1; j < 9; ++j) acc += bu[j] * th2[i * 17 + j];
#pragma unroll
        for (int j = 0; j < 8; ++j)     acc += bt[j] * th2[i * 17 + 9 + j];
        phi += bu[i] * acc;
    }
#pragma unroll
    for (int a = 0; a < 8; ++a) {
        float acc = th1[9 + a];
#pragma unroll
        for (int b2 = a + 1; b2 < 8; ++b2) acc += bt[b2] * th2[(9 + a) * 17 + 9 + b2];
        phi += bt[a] * acc;
    }
    // alpha = atan2(sin^2, cos^2); cos/sin of alpha directly (no atan needed)
    float sp, cp;
    sincosf(phi, &sp, &cp);
    float c2 = cp * cp, s2 = sp * sp;
    float d = c2 * c2 + s2 * s2;           // >= 0.25 always
    float r = rsqrtf(d);
    r = r * (1.5f - 0.5f * d * r * r);     // one Newton step
    tab[(size_t)n * 131072 + ((hi << 8) | tid)] = make_float2(c2 * r, s2 * r);
}

// ============================ K2: main fused ============================
// Triple pass on bits (pa, pa-1, pa-2), pa in {12,9,6}; 1 group of 32 amps/thread.
template <bool NEUR>
__device__ __forceinline__ void triple_hi(float* st, int pa,
    const float2* tA, const float2* tB, const float2* tC,
    float cA, float sA, float cB, float sB, float cC, float sC)
{
    const int pb = pa - 1, pc = pa - 2;
    const int h = threadIdx.x;
    const int lowb = pc - 2;                 // >= 2
    const int low = h & ((1 << lowb) - 1);
    const int high = h >> lowb;
    const int i0 = (high << (pa + 1)) | (low << 2);
    const int oa = 1 << pa, ob = 1 << pb, oc = 1 << pc;
    __syncthreads();
    float4 Q000 = ldsld4(st, i0),            Q001 = ldsld4(st, i0 + oc);
    float4 Q010 = ldsld4(st, i0 + ob),       Q011 = ldsld4(st, i0 + ob + oc);
    float4 Q100 = ldsld4(st, i0 + oa),       Q101 = ldsld4(st, i0 + oa + oc);
    float4 Q110 = ldsld4(st, i0 + oa + ob),  Q111 = ldsld4(st, i0 + oa + ob + oc);
    if (NEUR) {
        const int db = 1 << (pb - 1), dc = 1 << (pc - 1);
        {   // level A: target bit pa
            const int x0 = (high << (pa - 1)) | (low << 1);
            float4 e00 = T4(tA, x0), e01 = T4(tA, x0 + dc),
                   e10 = T4(tA, x0 + db), e11 = T4(tA, x0 + db + dc);
            rot4(Q000, Q100, e00); rot4(Q001, Q101, e01);
            rot4(Q010, Q110, e10); rot4(Q011, Q111, e11);
        }
        {   // level B: target bit pb (ja -> db, jc -> dc)
            const int x0 = (high << pb) | (low << 1);
            float4 e00 = T4(tB, x0), e01 = T4(tB, x0 + dc),
                   e10 = T4(tB, x0 + db), e11 = T4(tB, x0 + db + dc);
            rot4(Q000, Q010, e00); rot4(Q001, Q011, e01);
            rot4(Q100, Q110, e10); rot4(Q101, Q111, e11);
        }
        {   // level C: target bit pc (ja -> 1<<pc, jb -> dc)
            const int x0 = (high << (pc + 1)) | (low << 1);
            const int da = 1 << pc;
            float4 e00 = T4(tC, x0), e01 = T4(tC, x0 + dc),
                   e10 = T4(tC, x0 + da), e11 = T4(tC, x0 + da + dc);
            rot4(Q000, Q001, e00); rot4(Q010, Q011, e01);
            rot4(Q100, Q101, e10); rot4(Q110, Q111, e11);
        }
    } else {
        float4 eA = make_float4(cA, sA, cA, sA);
        rot4(Q000, Q100, eA); rot4(Q001, Q101, eA);
        rot4(Q010, Q110, eA); rot4(Q011, Q111, eA);
        float4 eB = make_float4(cB, sB, cB, sB);
        rot4(Q000, Q010, eB); rot4(Q001, Q011, eB);
        rot4(Q100, Q110, eB); rot4(Q101, Q111, eB);
        float4 eC = make_float4(cC, sC, cC, sC);
        rot4(Q000, Q001, eC); rot4(Q010, Q011, eC);
        rot4(Q100, Q101, eC); rot4(Q110, Q111, eC);
    }
    ldsst4(st, i0, Q000);            ldsst4(st, i0 + oc, Q001);
    ldsst4(st, i0 + ob, Q010);       ldsst4(st, i0 + ob + oc, Q011);
    ldsst4(st, i0 + oa, Q100);       ldsst4(st, i0 + oa + oc, Q101);
    ldsst4(st, i0 + oa + ob, Q110);  ldsst4(st, i0 + oa + ob + oc, Q111);
}

// Triple pass on bits (3,2,1): 16 consecutive floats per group, 2 groups/thread.
template <bool NEUR>
__device__ __forceinline__ void triple_lo(float* st,
    const float2* tA, const float2* tB, const float2* tC,
    float cA, float sA, float cB, float sB, float cC, float sC)
{
    __syncthreads();
#pragma unroll
    for (int g = 0; g < 2; ++g) {
        const int h = threadIdx.x + (g << 8);   // 0..511
        const int i0 = h << 4;
        float4 P00 = ldsld4(st, i0),     P01 = ldsld4(st, i0 + 4);
        float4 P10 = ldsld4(st, i0 + 8), P11 = ldsld4(st, i0 + 12);
        if (NEUR) {
            const int x0 = h << 2;
            float4 eA0 = T4(tA, x0), eA1 = T4(tA, x0 + 2);
            rot4(P00, P10, eA0); rot4(P01, P11, eA1);          // bit 3
            float4 eB0 = T4(tB, x0), eB1 = T4(tB, x0 + 2);
            rot4(P00, P01, eB0); rot4(P10, P11, eB1);          // bit 2
            float4 c0 = T4(tC, x0), c1 = T4(tC, x0 + 2);       // bit 1 (in-quad)
            rotq(P00, c0.x, c0.y); rotq(P01, c0.z, c0.w);
            rotq(P10, c1.x, c1.y); rotq(P11, c1.z, c1.w);
        } else {
            float4 eA = make_float4(cA, sA, cA, sA);
            rot4(P00, P10, eA); rot4(P01, P11, eA);
            float4 eB = make_float4(cB, sB, cB, sB);
            rot4(P00, P01, eB); rot4(P10, P11, eB);
            rotq(P00, cC, sC); rotq(P01, cC, sC);
            rotq(P10, cC, sC); rotq(P11, cC, sC);
        }
        ldsst4(st, i0, P00);     ldsst4(st, i0 + 4, P01);
        ldsst4(st, i0 + 8, P10); ldsst4(st, i0 + 12, P11);
    }
}

__global__ __launch_bounds__(256, 4) void main_kernel(
    const float* __restrict__ batch, const float* __restrict__ w_u,
    const int* __restrict__ inputs, const float2* __restrict__ tab,
    float* __restrict__ psi)
{
    __shared__ __align__(16) float st[8192];
    const int tid = threadIdx.x;
    const int blk = blockIdx.x;
    // XCD-clustered mapping: same-vt blocks land on same XCD (tables L2-resident)
    const int xcd = blk & 7, s = blk >> 3;
    const int vt = (xcd << 3) | (s >> 5);    // table inout value
    const int b = s & 31;
    int fb = 0;
#pragma unroll
    for (int i = 0; i < 6; ++i) fb |= (inputs[b * 6 + i] & 1) << (5 - i);
    const int u = vt ^ fb;                    // physical block (both bitflips folded)

    const float* src = batch + ((size_t)b << 19) + ((size_t)u << 13);
#pragma unroll
    for (int k = 0; k < 8; ++k) {
        int i4 = (k * 256 + tid) * 4;
        float4 v = *(const float4*)&src[i4];
        *(float4*)&st[SW(i4)] = v;
    }

    const float2* tb = tab + (vt << 11);
#define TN(j) (tb + (size_t)(j) * 131072)
    // input layer (neurons j=0..11, target bit 12-j)
    triple_hi<true>(st, 12, TN(0), TN(1), TN(2), 0, 0, 0, 0, 0, 0);
    triple_hi<true>(st, 9,  TN(3), TN(4), TN(5), 0, 0, 0, 0, 0, 0);
    triple_hi<true>(st, 6,  TN(6), TN(7), TN(8), 0, 0, 0, 0, 0, 0);
    triple_lo<true>(st, TN(9), TN(10), TN(11), 0, 0, 0, 0, 0, 0);

#pragma unroll 1
    for (int st2 = 0; st2 < 3; ++st2) {
        const float* wu = w_u + st2 * 12;
        float c0, s0, c1, s1, c2, s2;
        sincosf(wu[0], &s0, &c0); sincosf(wu[1], &s1, &c1); sincosf(wu[2], &s2, &c2);
        triple_hi<false>(st, 12, 0, 0, 0, c0, s0, c1, s1, c2, s2);
        sincosf(wu[3], &s0, &c0); sincosf(wu[4], &s1, &c1); sincosf(wu[5], &s2, &c2);
        triple_hi<false>(st, 9, 0, 0, 0, c0, s0, c1, s1, c2, s2);
        sincosf(wu[6], &s0, &c0); sincosf(wu[7], &s1, &c1); sincosf(wu[8], &s2, &c2);
        triple_hi<false>(st, 6, 0, 0, 0, c0, s0, c1, s1, c2, s2);
        sincosf(wu[9], &s0, &c0); sincosf(wu[10], &s1, &c1); sincosf(wu[11], &s2, &c2);
        triple_lo<false>(st, 0, 0, 0, c0, s0, c1, s1, c2, s2);

        const int nb = 12 + st2 * 12;
        triple_hi<true>(st, 12, TN(nb + 0), TN(nb + 1), TN(nb + 2), 0, 0, 0, 0, 0, 0);
        triple_hi<true>(st, 9,  TN(nb + 3), TN(nb + 4), TN(nb + 5), 0, 0, 0, 0, 0, 0);
        triple_hi<true>(st, 6,  TN(nb + 6), TN(nb + 7), TN(nb + 8), 0, 0, 0, 0, 0, 0);
        triple_lo<true>(st, TN(nb + 9), TN(nb + 10), TN(nb + 11), 0, 0, 0, 0, 0, 0);
    }
#undef TN
    __syncthreads();
    float* dst = psi + ((size_t)b << 19) + ((size_t)u << 13);
#pragma unroll
    for (int k = 0; k < 8; ++k) {
        int i4 = (k * 256 + tid) * 4;
        *(float4*)&dst[i4] = *(const float4*)&st[SW(i4)];
    }
}

// ============================ K3: output layer ============================
// One thread per low-13-bit column; 64 inout amps in registers.
__global__ __launch_bounds__(256, 2) void out_kernel(
    const float2* __restrict__ tab, float* __restrict__ psi)
{
    const int tid = threadIdx.x;
    const int b = blockIdx.x >> 5;
    const int col = ((blockIdx.x & 31) << 8) | tid;
    float* base = psi + ((size_t)b << 19) + col;
    float a[64];
#pragma unroll
    for (int k = 0; k < 64; ++k) a[k] = base[(size_t)k << 13];
    const int w12 = col >> 1;
#pragma unroll
    for (int j = 0; j < 6; ++j) {
        const float2* tj = tab + (size_t)(48 + j) * 131072 + w12;
        const int q = 5 - j;
#pragma unroll
        for (int m = 0; m < 32; ++m) {
            int k0 = ((m >> q) << (q + 1)) | (m & ((1 << q) - 1));
            int k1 = k0 | (1 << q);
            float2 e = tj[(size_t)m << 12];
            float a0 = a[k0], a1 = a[k1];
            a[k0] = e.x * a0 - e.y * a1;
            a[k1] = e.y * a0 + e.x * a1;
        }
    }
#pragma unroll
    for (int k = 0; k < 64; ++k) base[(size_t)k << 13] = a[k];
}

// ============================ K4: probs ============================
__global__ __launch_bounds__(256) void probs_kernel(
    const float* __restrict__ psi, float* __restrict__ probs)
{
    const int b = blockIdx.x >> 6, v = blockIdx.x & 63;
    const float* p = psi + ((size_t)b << 19) + ((size_t)v << 13);
    const int tid = threadIdx.x;
    float acc = 0.f;
#pragma unroll
    for (int k = 0; k < 8; ++k) {
        float4 t = *(const float4*)&p[(k * 256 + tid) * 4];
        acc += t.x * t.x + t.y * t.y + t.z * t.z + t.w * t.w;
    }
#pragma unroll
    for (int o = 32; o > 0; o >>= 1) acc += __shfl_down(acc, o);
    __shared__ float red[4];
    if ((tid & 63) == 0) red[tid >> 6] = acc;
    __syncthreads();
    if (tid == 0) probs[b * 64 + v] = red[0] + red[1] + red[2] + red[3];
}

// ============================ launch ============================
extern "C" void kernel_launch(void* const* d_in, const int* in_sizes, int n_in,
                              void* d_out, int out_size, void* d_ws, size_t ws_size,
                              hipStream_t stream)
{
    const float* batch  = (const float*)d_in[0];
    const float* w_in1  = (const float*)d_in[1];
    const float* w_in2  = (const float*)d_in[2];
    const float* w_u    = (const float*)d_in[3];
    const float* w_k1   = (const float*)d_in[4];
    const float* w_k2   = (const float*)d_in[5];
    const float* w_out1 = (const float*)d_in[6];
    const float* w_out2 = (const float*)d_in[7];
    const int*   inputs = (const int*)d_in[8];
    float* probs = (float*)d_out;
    float* psi   = (float*)d_out + 2048;      // 32*64 probs, then 32*2^19 psi
    float2* tab  = (float2*)d_ws;             // 54 * 131072 * 8B = 54 MiB

    tables_kernel<<<dim3(512, 54), 256, 0, stream>>>(w_in1, w_in2, w_k1, w_k2,
                                                     w_out1, w_out2, tab);
    main_kernel<<<2048, 256, 0, stream>>>(batch, w_u, inputs, tab, psi);
    out_kernel<<<1024, 256, 0, stream>>>(tab, psi);
    probs_kernel<<<2048, 256, 0, stream>>>(psi, probs);
}